// Round 14
// baseline (475.610 us; speedup 1.0000x reference)
//
#include <hip/hip_runtime.h>
#include <math.h>

#define FDIM 256
#define NGRAPH 128
#define NCLASS 10

typedef short short8 __attribute__((ext_vector_type(8)));
typedef float floatx4 __attribute__((ext_vector_type(4)));

// fp32 <-> bf16 helpers (RNE)
static __device__ __forceinline__ unsigned short f2bf(float f) {
    unsigned u = __float_as_uint(f);
    u += 0x7FFF + ((u >> 16) & 1);
    return (unsigned short)(u >> 16);
}

// ---------------- prep: count+slot | packw x3 | zero g (one dispatch) ----------------
// slot is 16-bit (max in-degree ~50 << 65536)

__global__ __launch_bounds__(256) void prep_kernel(const int* __restrict__ dst,
                                                   int* __restrict__ cnt,
                                                   unsigned short* __restrict__ slot,
                                                   int E, int nCnt,
                                                   const float* __restrict__ W0,
                                                   const float* __restrict__ W1,
                                                   const float* __restrict__ W2,
                                                   unsigned short* __restrict__ Bp0,
                                                   unsigned short* __restrict__ Bp1,
                                                   unsigned short* __restrict__ Bp2,
                                                   float4* __restrict__ g4) {
    const int b = blockIdx.x;
    const int t = threadIdx.x;
    if (b < nCnt) {
        int e = b * 256 + t;
        if (e < E) slot[e] = (unsigned short)atomicAdd(&cnt[dst[e]], 1);
        return;
    }
    const int b2 = b - nCnt;
    if (b2 >= 96) {
        g4[(size_t)(b2 - 96) * 256 + t] = (float4){0.f, 0.f, 0.f, 0.f};
        return;
    }
    const float* W = (b2 < 32) ? W0 : (b2 < 64) ? W1 : W2;
    unsigned short* Bp = (b2 < 32) ? Bp0 : (b2 < 64) ? Bp1 : Bp2;
    int idx = (b2 & 31) * 256 + t;   // [0, 8192)
    int kstep = idx >> 10;
    int ntile = (idx >> 6) & 15;
    int lane  = idx & 63;
    int col   = ntile * 16 + (lane & 15);
    int krow  = kstep * 32 + (lane >> 4) * 8;
    unsigned short o[8];
#pragma unroll
    for (int j = 0; j < 8; j++) o[j] = f2bf(W[(size_t)(krow + j) * FDIM + col]);
    *(uint4*)(Bp + (size_t)idx * 8) = *(uint4*)o;
}

// ---------------- CSR scan (single dispatch; block self-computes its offset) ----------------

__global__ __launch_bounds__(256) void csr_scan(const int* __restrict__ cnt,
                                                int* __restrict__ rowptr,
                                                float* __restrict__ dinv, int N, int E) {
    __shared__ int redo[256];
    __shared__ int tsum[256];
    const int t = threadIdx.x;
    const int bid = blockIdx.x;

    // prefix over all cnt before this block's 1024-chunk (grid-stride, L2-resident)
    int pre = 0;
    const int lim = bid * 1024;
    for (int i = t; i < lim; i += 256) pre += cnt[i];
    redo[t] = pre;
    __syncthreads();
    for (int off = 128; off > 0; off >>= 1) {
        if (t < off) redo[t] += redo[t + off];
        __syncthreads();
    }
    const int blockoff = redo[0];
    __syncthreads();

    const int base = bid * 1024 + t * 4;
    int c[4];
    int s = 0;
#pragma unroll
    for (int i = 0; i < 4; i++) {
        c[i] = (base + i < N) ? cnt[base + i] : 0;
        s += c[i];
    }
    tsum[t] = s;
    __syncthreads();
    for (int off = 1; off < 256; off <<= 1) {
        int v = (t >= off) ? tsum[t - off] : 0;
        __syncthreads();
        tsum[t] += v;
        __syncthreads();
    }
    int run = blockoff + ((t == 0) ? 0 : tsum[t - 1]);
#pragma unroll
    for (int i = 0; i < 4; i++) {
        int idx = base + i;
        if (idx < N) {
            rowptr[idx] = run;
            dinv[idx] = rsqrtf((float)c[i] + 1.0f);   // +1 = self loop
            run += c[i];
        }
    }
    if (bid == 0 && t == 0) rowptr[N] = E;
}

// ---------------- GEMM tile body: 16 rows/wave, full 256 cols ----------------

static __device__ __forceinline__ void gemm_tile16_f32(const float* __restrict__ A,
                                                       const unsigned short* __restrict__ Bp,
                                                       unsigned short* __restrict__ C,
                                                       int M, int tile) {
    const int wave = threadIdx.x >> 6;
    const int lane = threadIdx.x & 63;
    const int quad = lane >> 4;
    const int m    = lane & 15;
    const int row0 = tile * 64 + wave * 16;

    const int r0 = min(row0 + m, M - 1);          // x unpadded: clamp
    const float* arow = A + (size_t)r0 * FDIM + quad * 8;

    floatx4 acc[16];
#pragma unroll
    for (int i = 0; i < 16; i++) acc[i] = (floatx4){0.f, 0.f, 0.f, 0.f};

#pragma unroll
    for (int kstep = 0; kstep < 8; kstep++) {
        float4 p0 = *(const float4*)(arow + kstep * 32);
        float4 p1 = *(const float4*)(arow + kstep * 32 + 4);
        short8 a;
        a[0] = (short)f2bf(p0.x); a[1] = (short)f2bf(p0.y);
        a[2] = (short)f2bf(p0.z); a[3] = (short)f2bf(p0.w);
        a[4] = (short)f2bf(p1.x); a[5] = (short)f2bf(p1.y);
        a[6] = (short)f2bf(p1.z); a[7] = (short)f2bf(p1.w);
#pragma unroll
        for (int nt = 0; nt < 16; nt++) {
            short8 b = *(const short8*)((const short*)Bp +
                         ((size_t)(kstep * 16 + nt) * 64 + lane) * 8);
            acc[nt] = __builtin_amdgcn_mfma_f32_16x16x32_bf16(a, b, acc[nt], 0, 0, 0);
        }
    }
#pragma unroll
    for (int nt = 0; nt < 16; nt++) {
        int col = nt * 16 + m;
#pragma unroll
        for (int r = 0; r < 4; r++) {
            int row = row0 + quad * 4 + r;
            if (row < M) C[(size_t)row * FDIM + col] = f2bf(acc[nt][r]);
        }
    }
}

// combo: blocks [0,ng) = gemm0 tiles (fp32 A); blocks [ng, ng+nfill) = CSR fill (16-bit)
__global__ __launch_bounds__(256) void gemm0_fill_kernel(const float* __restrict__ x,
                                                         const unsigned short* __restrict__ Bp0,
                                                         unsigned short* __restrict__ H,
                                                         int M, int ng,
                                                         const int* __restrict__ src,
                                                         const int* __restrict__ dst,
                                                         const int* __restrict__ rowptr,
                                                         const unsigned short* __restrict__ slot,
                                                         unsigned short* __restrict__ srcs, int E) {
    if ((int)blockIdx.x < ng) {
        gemm_tile16_f32(x, Bp0, H, M, blockIdx.x);
        return;
    }
    int e = (blockIdx.x - ng) * 256 + threadIdx.x;
    if (e < E) srcs[rowptr[dst[e]] + (int)slot[e]] = (unsigned short)src[e];
}

// bf16 GEMM: standalone dispatch, 16 rows/wave
__global__ __launch_bounds__(256) void mfma_gemm(const unsigned short* __restrict__ A,
                                                 const unsigned short* __restrict__ Bp,
                                                 unsigned short* __restrict__ C, int M) {
    const int wave = threadIdx.x >> 6;
    const int lane = threadIdx.x & 63;
    const int quad = lane >> 4;
    const int m    = lane & 15;
    const int row0 = blockIdx.x * 64 + wave * 16;

    const short* arow = (const short*)A + (size_t)(row0 + m) * FDIM + quad * 8;

    floatx4 acc[16];
#pragma unroll
    for (int i = 0; i < 16; i++) acc[i] = (floatx4){0.f, 0.f, 0.f, 0.f};

#pragma unroll
    for (int kstep = 0; kstep < 8; kstep++) {
        short8 a = *(const short8*)(arow + kstep * 32);
#pragma unroll
        for (int nt = 0; nt < 16; nt++) {
            short8 b = *(const short8*)((const short*)Bp +
                         ((size_t)(kstep * 16 + nt) * 64 + lane) * 8);
            acc[nt] = __builtin_amdgcn_mfma_f32_16x16x32_bf16(a, b, acc[nt], 0, 0, 0);
        }
    }
#pragma unroll
    for (int nt = 0; nt < 16; nt++) {
        int col = nt * 16 + m;
#pragma unroll
        for (int r = 0; r < 4; r++) {
            int row = row0 + quad * 4 + r;
            if (row < M) C[(size_t)row * FDIM + col] = f2bf(acc[nt][r]);
        }
    }
}

// ---------------- gather core (16-bit srcs) ----------------

static __device__ __forceinline__ void accum8(float* acc, uint4 v, float nm) {
    const unsigned* u = (const unsigned*)&v;
#pragma unroll
    for (int i = 0; i < 4; i++) {
        acc[2 * i]     += nm * __uint_as_float(u[i] << 16);
        acc[2 * i + 1] += nm * __uint_as_float(u[i] & 0xFFFF0000u);
    }
}

static __device__ __forceinline__ void gather_node(const unsigned short* __restrict__ h,
                                                   const int* __restrict__ rowptr,
                                                   const unsigned short* __restrict__ srcs,
                                                   const float* __restrict__ dinv,
                                                   const float* __restrict__ bias,
                                                   int node, int lane, float* acc) {
    const float di = dinv[node];
    {
        uint4 sv = *(const uint4*)(h + (size_t)node * FDIM + lane * 8);
        const unsigned* u = (const unsigned*)&sv;
#pragma unroll
        for (int i = 0; i < 4; i++) {
            acc[2 * i]     = di * di * __uint_as_float(u[i] << 16);
            acc[2 * i + 1] = di * di * __uint_as_float(u[i] & 0xFFFF0000u);
        }
        float4 b0 = *(const float4*)(bias + lane * 8);
        float4 b1 = *(const float4*)(bias + lane * 8 + 4);
        acc[0] += b0.x; acc[1] += b0.y; acc[2] += b0.z; acc[3] += b0.w;
        acc[4] += b1.x; acc[5] += b1.y; acc[6] += b1.z; acc[7] += b1.w;
    }
    const int beg = rowptr[node];
    const int end = rowptr[node + 1];
    int p = beg;
    for (; p + 4 <= end; p += 4) {
        int s0 = srcs[p], s1 = srcs[p + 1], s2 = srcs[p + 2], s3 = srcs[p + 3];
        float n0 = dinv[s0] * di, n1 = dinv[s1] * di;
        float n2 = dinv[s2] * di, n3 = dinv[s3] * di;
        uint4 v0 = *(const uint4*)(h + (size_t)s0 * FDIM + lane * 8);
        uint4 v1 = *(const uint4*)(h + (size_t)s1 * FDIM + lane * 8);
        uint4 v2 = *(const uint4*)(h + (size_t)s2 * FDIM + lane * 8);
        uint4 v3 = *(const uint4*)(h + (size_t)s3 * FDIM + lane * 8);
        accum8(acc, v0, n0);
        accum8(acc, v1, n1);
        accum8(acc, v2, n2);
        accum8(acc, v3, n3);
    }
    for (; p < end; p++) {
        int s = srcs[p];
        float nm = dinv[s] * di;
        uint4 v = *(const uint4*)(h + (size_t)s * FDIM + lane * 8);
        accum8(acc, v, nm);
    }
#pragma unroll
    for (int i = 0; i < 8; i++) acc[i] = fmaxf(acc[i], 0.0f);
}

__global__ __launch_bounds__(256) void gather_kernel(const unsigned short* __restrict__ h,
                                                     const int* __restrict__ rowptr,
                                                     const unsigned short* __restrict__ srcs,
                                                     const float* __restrict__ dinv,
                                                     const float* __restrict__ bias,
                                                     unsigned short* __restrict__ out, int N) {
    const int node = blockIdx.x * 8 + (threadIdx.x >> 5);
    const int lane = threadIdx.x & 31;
    if (node >= N) return;
    float acc[8];
    gather_node(h, rowptr, srcs, dinv, bias, node, lane, acc);
    unsigned short o[8];
#pragma unroll
    for (int i = 0; i < 8; i++) o[i] = f2bf(acc[i]);
    *(uint4*)(out + (size_t)node * FDIM + lane * 8) = *(uint4*)o;
}

// last layer: gather + pool fused
__global__ __launch_bounds__(256) void gather_pool_kernel(const unsigned short* __restrict__ h,
                                                          const int* __restrict__ rowptr,
                                                          const unsigned short* __restrict__ srcs,
                                                          const float* __restrict__ dinv,
                                                          const float* __restrict__ bias,
                                                          const int* __restrict__ batch,
                                                          float* __restrict__ g, int N) {
    __shared__ float red[8][FDIM];   // 8 KB
    __shared__ int bid[8];
    const int hw   = threadIdx.x >> 5;
    const int lane = threadIdx.x & 31;
    const int node = blockIdx.x * 8 + hw;

    float acc[8] = {0.f, 0.f, 0.f, 0.f, 0.f, 0.f, 0.f, 0.f};
    if (node < N) gather_node(h, rowptr, srcs, dinv, bias, node, lane, acc);
#pragma unroll
    for (int i = 0; i < 8; i++) red[hw][lane * 8 + i] = acc[i];
    if (lane == 0) bid[hw] = (node < N) ? batch[node] : -1;
    __syncthreads();

    const int f = threadIdx.x;
    int cur = -1;
    float run = 0.0f;
    for (int i = 0; i < 8; i++) {
        int b = bid[i];
        if (b < 0) break;
        if (b != cur) {
            if (cur >= 0) atomicAdd(&g[(size_t)cur * FDIM + f], run);
            cur = b;
            run = 0.0f;
        }
        run += red[i][f];
    }
    if (cur >= 0) atomicAdd(&g[(size_t)cur * FDIM + f], run);
}

// ---------------- fused FC head ----------------

__global__ __launch_bounds__(256) void fc_head_kernel(const float* __restrict__ g,
                                                      const float* __restrict__ fc1W,
                                                      const float* __restrict__ fc1b,
                                                      const float* __restrict__ fc2W,
                                                      const float* __restrict__ fc2b,
                                                      float* __restrict__ out) {
    __shared__ float gs[FDIM];
    __shared__ float part[4][FDIM];
    __shared__ float hs[FDIM];
    __shared__ float p2[256];
    __shared__ float logits[NCLASS];
    const int r = blockIdx.x;
    const int t = threadIdx.x;
    const int w = t >> 6;
    const int l = t & 63;

    gs[t] = g[(size_t)r * FDIM + t];
    __syncthreads();

    float a[4] = {0.f, 0.f, 0.f, 0.f};
    for (int kk = 0; kk < 64; kk++) {
        int k = w * 64 + kk;
        float gv = gs[k];
#pragma unroll
        for (int j = 0; j < 4; j++) a[j] += gv * fc1W[(size_t)k * FDIM + j * 64 + l];
    }
#pragma unroll
    for (int j = 0; j < 4; j++) part[w][j * 64 + l] = a[j];
    __syncthreads();

    float s1 = part[0][t] + part[1][t] + part[2][t] + part[3][t] + fc1b[t];
    hs[t] = fmaxf(s1, 0.0f);
    __syncthreads();

    float a2 = 0.0f;
    const int c = t & 15;
    if (c < NCLASS) {
        int k0 = (t >> 4) * 16;
        for (int kk = 0; kk < 16; kk++)
            a2 += hs[k0 + kk] * fc2W[(size_t)(k0 + kk) * NCLASS + c];
    }
    p2[t] = a2;
    __syncthreads();

    if (t < NCLASS) {
        float s2 = fc2b[t];
        for (int seg = 0; seg < 16; seg++) s2 += p2[seg * 16 + t];
        logits[t] = s2;
    }
    __syncthreads();

    if (t == 0) {
        float mx = logits[0];
        for (int cc = 1; cc < NCLASS; cc++) mx = fmaxf(mx, logits[cc]);
        float ssum = 0.0f;
        for (int cc = 0; cc < NCLASS; cc++) ssum += expf(logits[cc] - mx);
        float lse = mx + logf(ssum);
        for (int cc = 0; cc < NCLASS; cc++) out[(size_t)r * NCLASS + cc] = logits[cc] - lse;
    }
}

// ---------------- launcher ----------------

extern "C" void kernel_launch(void* const* d_in, const int* in_sizes, int n_in,
                              void* d_out, int out_size, void* d_ws, size_t ws_size,
                              hipStream_t stream) {
    const float* x     = (const float*)d_in[0];
    const int*   ei    = (const int*)d_in[1];
    const int*   batch = (const int*)d_in[2];
    const float* W0 = (const float*)d_in[3];  const float* b0 = (const float*)d_in[4];
    const float* W1 = (const float*)d_in[5];  const float* b1 = (const float*)d_in[6];
    const float* W2 = (const float*)d_in[7];  const float* b2 = (const float*)d_in[8];
    const float* fc1W = (const float*)d_in[9];  const float* fc1b = (const float*)d_in[10];
    const float* fc2W = (const float*)d_in[11]; const float* fc2b = (const float*)d_in[12];
    float* out = (float*)d_out;

    const int N = in_sizes[0] / FDIM;
    const int E = in_sizes[1] / 2;
    const int* src = ei;
    const int* dst = ei + E;
    const int Mpad = ((N + 63) / 64) * 64;
    const int nb   = (N + 1023) / 1024;
    const int nCnt = (E + 255) / 256;
    const int ng   = (N + 63) / 64;          // 64 rows per block (16/wave)

    // workspace layout (16B-aligned chunks)
    char* p = (char*)d_ws;
    unsigned short* S  = (unsigned short*)p; p += (size_t)Mpad * FDIM * 2;  // node state
    unsigned short* H  = (unsigned short*)p; p += (size_t)Mpad * FDIM * 2;  // GEMM out
    unsigned short* Wp0 = (unsigned short*)p; p += (size_t)8192 * 8 * 2;
    unsigned short* Wp1 = (unsigned short*)p; p += (size_t)8192 * 8 * 2;
    unsigned short* Wp2 = (unsigned short*)p; p += (size_t)8192 * 8 * 2;
    float* dinv = (float*)p; p += (size_t)N * 4;
    int*   cnt  = (int*)p;   p += (size_t)N * 4;
    int*   rowptr = (int*)p; p += (size_t)(N + 4) * 4;
    unsigned short* srcs = (unsigned short*)p; p += (((size_t)E * 2 + 15) & ~15ull);
    unsigned short* slot = (unsigned short*)p; p += (((size_t)E * 2 + 15) & ~15ull);
    float* g    = (float*)p;

    // ---- CSR build + weight pack ----
    hipMemsetAsync(cnt, 0, (size_t)N * sizeof(int), stream);
    prep_kernel<<<nCnt + 128, 256, 0, stream>>>(dst, cnt, slot, E, nCnt,
                                                W0, W1, W2, Wp0, Wp1, Wp2, (float4*)g);
    csr_scan<<<nb, 256, 0, stream>>>(cnt, rowptr, dinv, N, E);

    // ---- gemm0 (x@W0 -> H) + fill, one dispatch ----
    gemm0_fill_kernel<<<ng + nCnt, 256, 0, stream>>>(x, Wp0, H, N, ng,
                                                     src, dst, rowptr, slot, srcs, E);

    // ---- layers ----
    gather_kernel<<<(N + 7) / 8, 256, 0, stream>>>(H, rowptr, srcs, dinv, b0, S, N);
    mfma_gemm<<<ng, 256, 0, stream>>>(S, Wp1, H, N);
    gather_kernel<<<(N + 7) / 8, 256, 0, stream>>>(H, rowptr, srcs, dinv, b1, S, N);
    mfma_gemm<<<ng, 256, 0, stream>>>(S, Wp2, H, N);
    gather_pool_kernel<<<(N + 7) / 8, 256, 0, stream>>>(H, rowptr, srcs, dinv, b2,
                                                        batch, g, N);
    fc_head_kernel<<<NGRAPH, 256, 0, stream>>>(g, fc1W, fc1b, fc2W, fc2b, out);
}

// Round 15
// 443.960 us; speedup vs baseline: 1.0713x; 1.0713x over previous
//
#include <hip/hip_runtime.h>
#include <math.h>

#define FDIM 256
#define NGRAPH 128
#define NCLASS 10

typedef short short8 __attribute__((ext_vector_type(8)));
typedef float floatx4 __attribute__((ext_vector_type(4)));

// fp32 <-> bf16 helpers (RNE)
static __device__ __forceinline__ unsigned short f2bf(float f) {
    unsigned u = __float_as_uint(f);
    u += 0x7FFF + ((u >> 16) & 1);
    return (unsigned short)(u >> 16);
}

// ---------------- prep: count+slot | packw x3 | zero g (one dispatch) ----------------
// slot is 16-bit (max in-degree ~50 << 65536)

__global__ __launch_bounds__(256) void prep_kernel(const int* __restrict__ dst,
                                                   int* __restrict__ cnt,
                                                   unsigned short* __restrict__ slot,
                                                   int E, int nCnt,
                                                   const float* __restrict__ W0,
                                                   const float* __restrict__ W1,
                                                   const float* __restrict__ W2,
                                                   unsigned short* __restrict__ Bp0,
                                                   unsigned short* __restrict__ Bp1,
                                                   unsigned short* __restrict__ Bp2,
                                                   float4* __restrict__ g4) {
    const int b = blockIdx.x;
    const int t = threadIdx.x;
    if (b < nCnt) {
        int e = b * 256 + t;
        if (e < E) slot[e] = (unsigned short)atomicAdd(&cnt[dst[e]], 1);
        return;
    }
    const int b2 = b - nCnt;
    if (b2 >= 96) {
        g4[(size_t)(b2 - 96) * 256 + t] = (float4){0.f, 0.f, 0.f, 0.f};
        return;
    }
    const float* W = (b2 < 32) ? W0 : (b2 < 64) ? W1 : W2;
    unsigned short* Bp = (b2 < 32) ? Bp0 : (b2 < 64) ? Bp1 : Bp2;
    int idx = (b2 & 31) * 256 + t;   // [0, 8192)
    int kstep = idx >> 10;
    int ntile = (idx >> 6) & 15;
    int lane  = idx & 63;
    int col   = ntile * 16 + (lane & 15);
    int krow  = kstep * 32 + (lane >> 4) * 8;
    unsigned short o[8];
#pragma unroll
    for (int j = 0; j < 8; j++) o[j] = f2bf(W[(size_t)(krow + j) * FDIM + col]);
    *(uint4*)(Bp + (size_t)idx * 8) = *(uint4*)o;
}

// ---------------- CSR scan (two dispatches; R13 form) ----------------

__global__ __launch_bounds__(256) void csr_bsum(const int* __restrict__ cnt,
                                                int* __restrict__ bsum, int N) {
    __shared__ int red[256];
    const int t = threadIdx.x;
    const int base = blockIdx.x * 1024 + t * 4;
    int s = 0;
#pragma unroll
    for (int i = 0; i < 4; i++)
        if (base + i < N) s += cnt[base + i];
    red[t] = s;
    __syncthreads();
    for (int off = 128; off > 0; off >>= 1) {
        if (t < off) red[t] += red[t + off];
        __syncthreads();
    }
    if (t == 0) bsum[blockIdx.x] = red[0];
}

// scan2 with inlined block-offset (each block reduces bsum[0..bid)) — no bscan dispatch
__global__ __launch_bounds__(256) void csr_scan2(const int* __restrict__ cnt,
                                                 const int* __restrict__ bsum,
                                                 int* __restrict__ rowptr,
                                                 float* __restrict__ dinv, int N, int E) {
    __shared__ int redo[256];
    __shared__ int tsum[256];
    const int t = threadIdx.x;
    const int bid = blockIdx.x;

    int pre = 0;
    for (int i = t; i < bid; i += 256) pre += bsum[i];
    redo[t] = pre;
    __syncthreads();
    for (int off = 128; off > 0; off >>= 1) {
        if (t < off) redo[t] += redo[t + off];
        __syncthreads();
    }
    const int blockoff = redo[0];
    __syncthreads();

    const int base = bid * 1024 + t * 4;
    int c[4];
    int s = 0;
#pragma unroll
    for (int i = 0; i < 4; i++) {
        c[i] = (base + i < N) ? cnt[base + i] : 0;
        s += c[i];
    }
    tsum[t] = s;
    __syncthreads();
    for (int off = 1; off < 256; off <<= 1) {
        int v = (t >= off) ? tsum[t - off] : 0;
        __syncthreads();
        tsum[t] += v;
        __syncthreads();
    }
    int run = blockoff + ((t == 0) ? 0 : tsum[t - 1]);
#pragma unroll
    for (int i = 0; i < 4; i++) {
        int idx = base + i;
        if (idx < N) {
            rowptr[idx] = run;
            dinv[idx] = rsqrtf((float)c[i] + 1.0f);   // +1 = self loop
            run += c[i];
        }
    }
    if (bid == 0 && t == 0) rowptr[N] = E;
}

// ---------------- GEMM tile body: 16 rows/wave, full 256 cols ----------------

static __device__ __forceinline__ void gemm_tile16_f32(const float* __restrict__ A,
                                                       const unsigned short* __restrict__ Bp,
                                                       unsigned short* __restrict__ C,
                                                       int M, int tile) {
    const int wave = threadIdx.x >> 6;
    const int lane = threadIdx.x & 63;
    const int quad = lane >> 4;
    const int m    = lane & 15;
    const int row0 = tile * 64 + wave * 16;

    const int r0 = min(row0 + m, M - 1);          // x unpadded: clamp
    const float* arow = A + (size_t)r0 * FDIM + quad * 8;

    floatx4 acc[16];
#pragma unroll
    for (int i = 0; i < 16; i++) acc[i] = (floatx4){0.f, 0.f, 0.f, 0.f};

#pragma unroll
    for (int kstep = 0; kstep < 8; kstep++) {
        float4 p0 = *(const float4*)(arow + kstep * 32);
        float4 p1 = *(const float4*)(arow + kstep * 32 + 4);
        short8 a;
        a[0] = (short)f2bf(p0.x); a[1] = (short)f2bf(p0.y);
        a[2] = (short)f2bf(p0.z); a[3] = (short)f2bf(p0.w);
        a[4] = (short)f2bf(p1.x); a[5] = (short)f2bf(p1.y);
        a[6] = (short)f2bf(p1.z); a[7] = (short)f2bf(p1.w);
#pragma unroll
        for (int nt = 0; nt < 16; nt++) {
            short8 b = *(const short8*)((const short*)Bp +
                         ((size_t)(kstep * 16 + nt) * 64 + lane) * 8);
            acc[nt] = __builtin_amdgcn_mfma_f32_16x16x32_bf16(a, b, acc[nt], 0, 0, 0);
        }
    }
#pragma unroll
    for (int nt = 0; nt < 16; nt++) {
        int col = nt * 16 + m;
#pragma unroll
        for (int r = 0; r < 4; r++) {
            int row = row0 + quad * 4 + r;
            if (row < M) C[(size_t)row * FDIM + col] = f2bf(acc[nt][r]);
        }
    }
}

// combo: blocks [0,ng) = gemm0 tiles (fp32 A); blocks [ng, ng+nfill) = CSR fill (16-bit)
__global__ __launch_bounds__(256) void gemm0_fill_kernel(const float* __restrict__ x,
                                                         const unsigned short* __restrict__ Bp0,
                                                         unsigned short* __restrict__ H,
                                                         int M, int ng,
                                                         const int* __restrict__ src,
                                                         const int* __restrict__ dst,
                                                         const int* __restrict__ rowptr,
                                                         const unsigned short* __restrict__ slot,
                                                         unsigned short* __restrict__ srcs, int E) {
    if ((int)blockIdx.x < ng) {
        gemm_tile16_f32(x, Bp0, H, M, blockIdx.x);
        return;
    }
    int e = (blockIdx.x - ng) * 256 + threadIdx.x;
    if (e < E) srcs[rowptr[dst[e]] + (int)slot[e]] = (unsigned short)src[e];
}

// bf16 GEMM: standalone dispatch, 16 rows/wave
__global__ __launch_bounds__(256) void mfma_gemm(const unsigned short* __restrict__ A,
                                                 const unsigned short* __restrict__ Bp,
                                                 unsigned short* __restrict__ C, int M) {
    const int wave = threadIdx.x >> 6;
    const int lane = threadIdx.x & 63;
    const int quad = lane >> 4;
    const int m    = lane & 15;
    const int row0 = blockIdx.x * 64 + wave * 16;

    const short* arow = (const short*)A + (size_t)(row0 + m) * FDIM + quad * 8;

    floatx4 acc[16];
#pragma unroll
    for (int i = 0; i < 16; i++) acc[i] = (floatx4){0.f, 0.f, 0.f, 0.f};

#pragma unroll
    for (int kstep = 0; kstep < 8; kstep++) {
        short8 a = *(const short8*)(arow + kstep * 32);
#pragma unroll
        for (int nt = 0; nt < 16; nt++) {
            short8 b = *(const short8*)((const short*)Bp +
                         ((size_t)(kstep * 16 + nt) * 64 + lane) * 8);
            acc[nt] = __builtin_amdgcn_mfma_f32_16x16x32_bf16(a, b, acc[nt], 0, 0, 0);
        }
    }
#pragma unroll
    for (int nt = 0; nt < 16; nt++) {
        int col = nt * 16 + m;
#pragma unroll
        for (int r = 0; r < 4; r++) {
            int row = row0 + quad * 4 + r;
            if (row < M) C[(size_t)row * FDIM + col] = f2bf(acc[nt][r]);
        }
    }
}

// ---------------- gather core (16-bit srcs) ----------------

static __device__ __forceinline__ void accum8(float* acc, uint4 v, float nm) {
    const unsigned* u = (const unsigned*)&v;
#pragma unroll
    for (int i = 0; i < 4; i++) {
        acc[2 * i]     += nm * __uint_as_float(u[i] << 16);
        acc[2 * i + 1] += nm * __uint_as_float(u[i] & 0xFFFF0000u);
    }
}

static __device__ __forceinline__ void gather_node(const unsigned short* __restrict__ h,
                                                   const int* __restrict__ rowptr,
                                                   const unsigned short* __restrict__ srcs,
                                                   const float* __restrict__ dinv,
                                                   const float* __restrict__ bias,
                                                   int node, int lane, float* acc) {
    const float di = dinv[node];
    {
        uint4 sv = *(const uint4*)(h + (size_t)node * FDIM + lane * 8);
        const unsigned* u = (const unsigned*)&sv;
#pragma unroll
        for (int i = 0; i < 4; i++) {
            acc[2 * i]     = di * di * __uint_as_float(u[i] << 16);
            acc[2 * i + 1] = di * di * __uint_as_float(u[i] & 0xFFFF0000u);
        }
        float4 b0 = *(const float4*)(bias + lane * 8);
        float4 b1 = *(const float4*)(bias + lane * 8 + 4);
        acc[0] += b0.x; acc[1] += b0.y; acc[2] += b0.z; acc[3] += b0.w;
        acc[4] += b1.x; acc[5] += b1.y; acc[6] += b1.z; acc[7] += b1.w;
    }
    const int beg = rowptr[node];
    const int end = rowptr[node + 1];
    int p = beg;
    for (; p + 4 <= end; p += 4) {
        int s0 = srcs[p], s1 = srcs[p + 1], s2 = srcs[p + 2], s3 = srcs[p + 3];
        float n0 = dinv[s0] * di, n1 = dinv[s1] * di;
        float n2 = dinv[s2] * di, n3 = dinv[s3] * di;
        uint4 v0 = *(const uint4*)(h + (size_t)s0 * FDIM + lane * 8);
        uint4 v1 = *(const uint4*)(h + (size_t)s1 * FDIM + lane * 8);
        uint4 v2 = *(const uint4*)(h + (size_t)s2 * FDIM + lane * 8);
        uint4 v3 = *(const uint4*)(h + (size_t)s3 * FDIM + lane * 8);
        accum8(acc, v0, n0);
        accum8(acc, v1, n1);
        accum8(acc, v2, n2);
        accum8(acc, v3, n3);
    }
    for (; p < end; p++) {
        int s = srcs[p];
        float nm = dinv[s] * di;
        uint4 v = *(const uint4*)(h + (size_t)s * FDIM + lane * 8);
        accum8(acc, v, nm);
    }
#pragma unroll
    for (int i = 0; i < 8; i++) acc[i] = fmaxf(acc[i], 0.0f);
}

__global__ __launch_bounds__(256) void gather_kernel(const unsigned short* __restrict__ h,
                                                     const int* __restrict__ rowptr,
                                                     const unsigned short* __restrict__ srcs,
                                                     const float* __restrict__ dinv,
                                                     const float* __restrict__ bias,
                                                     unsigned short* __restrict__ out, int N) {
    const int node = blockIdx.x * 8 + (threadIdx.x >> 5);
    const int lane = threadIdx.x & 31;
    if (node >= N) return;
    float acc[8];
    gather_node(h, rowptr, srcs, dinv, bias, node, lane, acc);
    unsigned short o[8];
#pragma unroll
    for (int i = 0; i < 8; i++) o[i] = f2bf(acc[i]);
    *(uint4*)(out + (size_t)node * FDIM + lane * 8) = *(uint4*)o;
}

// last layer: gather + pool fused
__global__ __launch_bounds__(256) void gather_pool_kernel(const unsigned short* __restrict__ h,
                                                          const int* __restrict__ rowptr,
                                                          const unsigned short* __restrict__ srcs,
                                                          const float* __restrict__ dinv,
                                                          const float* __restrict__ bias,
                                                          const int* __restrict__ batch,
                                                          float* __restrict__ g, int N) {
    __shared__ float red[8][FDIM];   // 8 KB
    __shared__ int bid[8];
    const int hw   = threadIdx.x >> 5;
    const int lane = threadIdx.x & 31;
    const int node = blockIdx.x * 8 + hw;

    float acc[8] = {0.f, 0.f, 0.f, 0.f, 0.f, 0.f, 0.f, 0.f};
    if (node < N) gather_node(h, rowptr, srcs, dinv, bias, node, lane, acc);
#pragma unroll
    for (int i = 0; i < 8; i++) red[hw][lane * 8 + i] = acc[i];
    if (lane == 0) bid[hw] = (node < N) ? batch[node] : -1;
    __syncthreads();

    const int f = threadIdx.x;
    int cur = -1;
    float run = 0.0f;
    for (int i = 0; i < 8; i++) {
        int b = bid[i];
        if (b < 0) break;
        if (b != cur) {
            if (cur >= 0) atomicAdd(&g[(size_t)cur * FDIM + f], run);
            cur = b;
            run = 0.0f;
        }
        run += red[i][f];
    }
    if (cur >= 0) atomicAdd(&g[(size_t)cur * FDIM + f], run);
}

// ---------------- fused FC head ----------------

__global__ __launch_bounds__(256) void fc_head_kernel(const float* __restrict__ g,
                                                      const float* __restrict__ fc1W,
                                                      const float* __restrict__ fc1b,
                                                      const float* __restrict__ fc2W,
                                                      const float* __restrict__ fc2b,
                                                      float* __restrict__ out) {
    __shared__ float gs[FDIM];
    __shared__ float part[4][FDIM];
    __shared__ float hs[FDIM];
    __shared__ float p2[256];
    __shared__ float logits[NCLASS];
    const int r = blockIdx.x;
    const int t = threadIdx.x;
    const int w = t >> 6;
    const int l = t & 63;

    gs[t] = g[(size_t)r * FDIM + t];
    __syncthreads();

    float a[4] = {0.f, 0.f, 0.f, 0.f};
    for (int kk = 0; kk < 64; kk++) {
        int k = w * 64 + kk;
        float gv = gs[k];
#pragma unroll
        for (int j = 0; j < 4; j++) a[j] += gv * fc1W[(size_t)k * FDIM + j * 64 + l];
    }
#pragma unroll
    for (int j = 0; j < 4; j++) part[w][j * 64 + l] = a[j];
    __syncthreads();

    float s1 = part[0][t] + part[1][t] + part[2][t] + part[3][t] + fc1b[t];
    hs[t] = fmaxf(s1, 0.0f);
    __syncthreads();

    float a2 = 0.0f;
    const int c = t & 15;
    if (c < NCLASS) {
        int k0 = (t >> 4) * 16;
        for (int kk = 0; kk < 16; kk++)
            a2 += hs[k0 + kk] * fc2W[(size_t)(k0 + kk) * NCLASS + c];
    }
    p2[t] = a2;
    __syncthreads();

    if (t < NCLASS) {
        float s2 = fc2b[t];
        for (int seg = 0; seg < 16; seg++) s2 += p2[seg * 16 + t];
        logits[t] = s2;
    }
    __syncthreads();

    if (t == 0) {
        float mx = logits[0];
        for (int cc = 1; cc < NCLASS; cc++) mx = fmaxf(mx, logits[cc]);
        float ssum = 0.0f;
        for (int cc = 0; cc < NCLASS; cc++) ssum += expf(logits[cc] - mx);
        float lse = mx + logf(ssum);
        for (int cc = 0; cc < NCLASS; cc++) out[(size_t)r * NCLASS + cc] = logits[cc] - lse;
    }
}

// ---------------- launcher ----------------

extern "C" void kernel_launch(void* const* d_in, const int* in_sizes, int n_in,
                              void* d_out, int out_size, void* d_ws, size_t ws_size,
                              hipStream_t stream) {
    const float* x     = (const float*)d_in[0];
    const int*   ei    = (const int*)d_in[1];
    const int*   batch = (const int*)d_in[2];
    const float* W0 = (const float*)d_in[3];  const float* b0 = (const float*)d_in[4];
    const float* W1 = (const float*)d_in[5];  const float* b1 = (const float*)d_in[6];
    const float* W2 = (const float*)d_in[7];  const float* b2 = (const float*)d_in[8];
    const float* fc1W = (const float*)d_in[9];  const float* fc1b = (const float*)d_in[10];
    const float* fc2W = (const float*)d_in[11]; const float* fc2b = (const float*)d_in[12];
    float* out = (float*)d_out;

    const int N = in_sizes[0] / FDIM;
    const int E = in_sizes[1] / 2;
    const int* src = ei;
    const int* dst = ei + E;
    const int Mpad = ((N + 63) / 64) * 64;
    const int nb   = (N + 1023) / 1024;
    const int nCnt = (E + 255) / 256;
    const int ng   = (N + 63) / 64;          // 64 rows per block (16/wave)

    // workspace layout (16B-aligned chunks)
    char* p = (char*)d_ws;
    unsigned short* S  = (unsigned short*)p; p += (size_t)Mpad * FDIM * 2;  // node state
    unsigned short* H  = (unsigned short*)p; p += (size_t)Mpad * FDIM * 2;  // GEMM out
    unsigned short* Wp0 = (unsigned short*)p; p += (size_t)8192 * 8 * 2;
    unsigned short* Wp1 = (unsigned short*)p; p += (size_t)8192 * 8 * 2;
    unsigned short* Wp2 = (unsigned short*)p; p += (size_t)8192 * 8 * 2;
    float* dinv = (float*)p; p += (size_t)N * 4;
    int*   cnt  = (int*)p;   p += (size_t)N * 4;
    int*   rowptr = (int*)p; p += (size_t)(N + 4) * 4;
    int*   bsum = (int*)p;   p += (size_t)256 * 4;
    unsigned short* srcs = (unsigned short*)p; p += (((size_t)E * 2 + 15) & ~15ull);
    unsigned short* slot = (unsigned short*)p; p += (((size_t)E * 2 + 15) & ~15ull);
    float* g    = (float*)p;

    // ---- CSR build + weight pack ----
    hipMemsetAsync(cnt, 0, (size_t)N * sizeof(int), stream);
    prep_kernel<<<nCnt + 128, 256, 0, stream>>>(dst, cnt, slot, E, nCnt,
                                                W0, W1, W2, Wp0, Wp1, Wp2, (float4*)g);
    csr_bsum<<<nb, 256, 0, stream>>>(cnt, bsum, N);
    csr_scan2<<<nb, 256, 0, stream>>>(cnt, bsum, rowptr, dinv, N, E);

    // ---- gemm0 (x@W0 -> H) + fill, one dispatch ----
    gemm0_fill_kernel<<<ng + nCnt, 256, 0, stream>>>(x, Wp0, H, N, ng,
                                                     src, dst, rowptr, slot, srcs, E);

    // ---- layers ----
    gather_kernel<<<(N + 7) / 8, 256, 0, stream>>>(H, rowptr, srcs, dinv, b0, S, N);
    mfma_gemm<<<ng, 256, 0, stream>>>(S, Wp1, H, N);
    gather_kernel<<<(N + 7) / 8, 256, 0, stream>>>(H, rowptr, srcs, dinv, b1, S, N);
    mfma_gemm<<<ng, 256, 0, stream>>>(S, Wp2, H, N);
    gather_pool_kernel<<<(N + 7) / 8, 256, 0, stream>>>(H, rowptr, srcs, dinv, b2,
                                                        batch, g, N);
    fc_head_kernel<<<NGRAPH, 256, 0, stream>>>(g, fc1W, fc1b, fc2W, fc2b, out);
}